// Round 1
// baseline (284.559 us; speedup 1.0000x reference)
//
#include <hip/hip_runtime.h>
#include <hip/hip_bf16.h>
#include <stdint.h>

#define N_ROWS 50000
#define D 384
#define K 8
#define BATCH 512
#define NEGO 128
#define NEDGE 1024

__device__ __forceinline__ float wave_reduce_sum(float v) {
#pragma unroll
    for (int d = 1; d < 64; d <<= 1) v += __shfl_xor(v, d);
    return v;
}

// ---------------------------------------------------------------------------
// Kernel A: normalize virtual rows, G = Vn Vn^T + eps I, invert 8x8.
// One block, 64 threads (1 wave).
// ---------------------------------------------------------------------------
__global__ __launch_bounds__(64) void prep_kernel(const float* __restrict__ virt,
                                                  float* __restrict__ Vn,
                                                  float* __restrict__ Ginv) {
    __shared__ float Vs[K * D];
    __shared__ float Gs[K * K];
    int tid = threadIdx.x;
    for (int t = tid; t < K * D; t += 64) Vs[t] = virt[t];
    __syncthreads();
    for (int k = 0; k < K; ++k) {
        float ss = 0.f;
        for (int t = tid; t < D; t += 64) { float v = Vs[k * D + t]; ss += v * v; }
        ss = wave_reduce_sum(ss);
        float inv = 1.0f / sqrtf(ss + 1e-12f);
        for (int t = tid; t < D; t += 64) {
            float v = Vs[k * D + t] * inv;
            Vs[k * D + t] = v;
            Vn[k * D + t] = v;
        }
        __syncthreads();
    }
    int k = tid >> 3, m = tid & 7;
    float g = 0.f;
    for (int j = 0; j < D; ++j) g += Vs[k * D + j] * Vs[m * D + j];
    if (k == m) g += 1e-4f;
    Gs[tid] = g;
    __syncthreads();
    if (tid == 0) {
        float A[K][K], I8[K][K];
        for (int a = 0; a < K; ++a)
            for (int b2 = 0; b2 < K; ++b2) {
                A[a][b2] = Gs[a * K + b2];
                I8[a][b2] = (a == b2) ? 1.f : 0.f;
            }
        // Gauss-Jordan, no pivoting: G is SPD with diag ~= 1+1e-4.
        for (int p = 0; p < K; ++p) {
            float piv = 1.0f / A[p][p];
            for (int j = 0; j < K; ++j) { A[p][j] *= piv; I8[p][j] *= piv; }
            for (int r = 0; r < K; ++r)
                if (r != p) {
                    float f = A[r][p];
                    for (int j = 0; j < K; ++j) {
                        A[r][j] -= f * A[p][j];
                        I8[r][j] -= f * I8[p][j];
                    }
                }
        }
        for (int a = 0; a < K; ++a)
            for (int b2 = 0; b2 < K; ++b2) Ginv[a * K + b2] = I8[a][b2];
    }
}

// ---------------------------------------------------------------------------
// Kernel B: per-row projection removal + l2norm, write bf16 local.
// 1 wave per row, 4 rows per 256-thread block.
// ---------------------------------------------------------------------------
__global__ __launch_bounds__(256) void local_kernel(const float* __restrict__ emb,
                                                    const float* __restrict__ Vn,
                                                    const float* __restrict__ Ginv,
                                                    __hip_bfloat16* __restrict__ outb) {
    __shared__ float Vs[K * D];
    __shared__ float Gs[K * K];
    int tid = threadIdx.x;
    for (int t = tid; t < K * D; t += 256) Vs[t] = Vn[t];
    if (tid < K * K) Gs[tid] = Ginv[tid];
    __syncthreads();
    int w = tid >> 6, l = tid & 63;
    size_t row = (size_t)blockIdx.x * 4 + w;  // grid = 12500 -> exactly 50000
    const float* x = emb + row * D;
    float xv[6];
#pragma unroll
    for (int t = 0; t < 6; ++t) xv[t] = x[l + 64 * t];
    float ss = 0.f;
#pragma unroll
    for (int t = 0; t < 6; ++t) ss += xv[t] * xv[t];
    float pk[K];
#pragma unroll
    for (int k = 0; k < K; ++k) pk[k] = 0.f;
#pragma unroll
    for (int t = 0; t < 6; ++t) {
        int j = l + 64 * t;
#pragma unroll
        for (int k = 0; k < K; ++k) pk[k] += xv[t] * Vs[k * D + j];
    }
    ss = wave_reduce_sum(ss);
#pragma unroll
    for (int k = 0; k < K; ++k) pk[k] = wave_reduce_sum(pk[k]);
    float invn = 1.0f / sqrtf(ss + 1e-12f);
    float coef[K];
#pragma unroll
    for (int k = 0; k < K; ++k) {
        float c = 0.f;
#pragma unroll
        for (int m = 0; m < K; ++m) c += (pk[m] * invn) * Gs[m * K + k];
        coef[k] = c;
    }
    float rv[6];
    float rss = 0.f;
#pragma unroll
    for (int t = 0; t < 6; ++t) {
        int j = l + 64 * t;
        float r = xv[t] * invn;
#pragma unroll
        for (int k = 0; k < K; ++k) r -= coef[k] * Vs[k * D + j];
        rv[t] = r;
        rss += r * r;
    }
    rss = wave_reduce_sum(rss);
    float invr = 1.0f / sqrtf(rss + 1e-12f);
#pragma unroll
    for (int t = 0; t < 6; ++t)
        outb[row * D + l + 64 * t] = __float2bfloat16(rv[t] * invr);
}

// ---------------------------------------------------------------------------
// Kernel C: per ego-graph: gather X (bf16), sim = X X^T, gumbel softmax,
// adjacency bitmask, diff row-norms, per-batch raw score.
// One 512-thread block (8 waves) per batch.
// LDS X layout: XP[kk][row], kk = pair index (2 bf16 per u32), row stride 130
// -> bank = (2*kk + row) % 32, conflict-free (2-way) for both reads & writes.
// ---------------------------------------------------------------------------
__global__ __launch_bounds__(512) void batch_kernel(const __hip_bfloat16* __restrict__ localb,
                                                    const float* __restrict__ gumbel,
                                                    const int* __restrict__ idx_batch,
                                                    const int* __restrict__ edges_src,
                                                    const int* __restrict__ edges_dst,
                                                    float* __restrict__ scores) {
    __shared__ uint32_t XP[192 * 130];      // 99840 B
    __shared__ uint32_t adjmask[NEGO * 4];  // 2048 B
    __shared__ int idxs[NEGO];
    __shared__ float red[8];
    int tid = threadIdx.x;
    int b = blockIdx.x;
    if (tid < NEGO) idxs[tid] = idx_batch[b * NEGO + tid];
    adjmask[tid] = 0u;  // 512 entries, 512 threads
    __syncthreads();

    // ---- stage gathered rows into LDS (8 threads per row, 16B vectors) ----
    int srow = tid >> 3;
    int vg = tid & 7;
#pragma unroll
    for (int pass = 0; pass < 2; ++pass) {
        int r = srow + pass * 64;
        const uint4* src = (const uint4*)(localb + (size_t)idxs[r] * D);
#pragma unroll
        for (int it = 0; it < 6; ++it) {
            int vec = vg + it * 8;
            uint4 v = src[vec];
            int kk = vec * 4;
            XP[(kk + 0) * 130 + r] = v.x;
            XP[(kk + 1) * 130 + r] = v.y;
            XP[(kk + 2) * 130 + r] = v.z;
            XP[(kk + 3) * 130 + r] = v.w;
        }
    }
    // ---- adjacency bitmask from edge list ----
    for (int e = tid; e < NEDGE; e += 512) {
        int s = edges_src[b * NEDGE + e];
        int dd = edges_dst[b * NEDGE + e];
        atomicOr(&adjmask[s * 4 + (dd >> 5)], 1u << (dd & 31));
    }
    __syncthreads();

    int w = tid >> 6, l = tid & 63;
    float wave_score = 0.f;
    for (int g = 0; g < 4; ++g) {
        int i0 = w * 16 + g * 4;
        float acc[4][2];
#pragma unroll
        for (int r = 0; r < 4; ++r) { acc[r][0] = 0.f; acc[r][1] = 0.f; }
        for (int kk = 0; kk < 192; ++kk) {
            uint32_t u0 = XP[kk * 130 + l];
            uint32_t u1 = XP[kk * 130 + l + 64];
            float a0l = __uint_as_float(u0 << 16);
            float a0h = __uint_as_float(u0 & 0xFFFF0000u);
            float a1l = __uint_as_float(u1 << 16);
            float a1h = __uint_as_float(u1 & 0xFFFF0000u);
#pragma unroll
            for (int r = 0; r < 4; ++r) {
                uint32_t ub = XP[kk * 130 + i0 + r];
                float bl = __uint_as_float(ub << 16);
                float bh = __uint_as_float(ub & 0xFFFF0000u);
                acc[r][0] += bl * a0l + bh * a0h;
                acc[r][1] += bl * a1l + bh * a1h;
            }
        }
#pragma unroll
        for (int r = 0; r < 4; ++r) {
            int i = i0 + r;
            float s0 = acc[r][0], s1 = acc[r][1];
            if (l == i) s0 = -1e9f;
            if (l + 64 == i) s1 = -1e9f;
            const float* grow = gumbel + ((size_t)b * NEGO + i) * NEGO;
            float z0 = s0 + grow[l];
            float z1 = s1 + grow[l + 64];
            float m = fmaxf(z0, z1);
#pragma unroll
            for (int d = 1; d < 64; d <<= 1) m = fmaxf(m, __shfl_xor(m, d));
            float e0 = expf(z0 - m);
            float e1 = expf(z1 - m);
            float se = wave_reduce_sum(e0 + e1);
            float inv = 1.0f / se;
            float p0 = e0 * inv, p1 = e1 * inv;
            float a0 = (float)((adjmask[i * 4 + (l >> 5)] >> (l & 31)) & 1u);
            float a1 = (float)((adjmask[i * 4 + 2 + (l >> 5)] >> (l & 31)) & 1u);
            float d0 = a0 - p0, d1 = a1 - p1;
            float rs = wave_reduce_sum(d0 * d0 + d1 * d1);
            wave_score += sqrtf(rs);
        }
    }
    if (l == 0) red[w] = wave_score;
    __syncthreads();
    if (tid == 0) {
        float tot = 0.f;
#pragma unroll
        for (int ww = 0; ww < 8; ++ww) tot += red[ww];
        scores[b] = tot * (1.0f / (float)NEGO);
    }
}

// ---------------------------------------------------------------------------
// Kernel D: min-max normalize scores, write them, compute BCE loss.
// One block, 512 threads.
// ---------------------------------------------------------------------------
__global__ __launch_bounds__(512) void finalize_kernel(const float* __restrict__ scores,
                                                       const int* __restrict__ labels,
                                                       float* __restrict__ out) {
    __shared__ float rmn[8], rmx[8], rsum[8];
    int tid = threadIdx.x, w = tid >> 6, l = tid & 63;
    float s = scores[tid];
    float mn = s, mx = s;
#pragma unroll
    for (int d = 1; d < 64; d <<= 1) {
        mn = fminf(mn, __shfl_xor(mn, d));
        mx = fmaxf(mx, __shfl_xor(mx, d));
    }
    if (l == 0) { rmn[w] = mn; rmx[w] = mx; }
    __syncthreads();
    mn = rmn[0]; mx = rmx[0];
#pragma unroll
    for (int ww = 1; ww < 8; ++ww) {
        mn = fminf(mn, rmn[ww]);
        mx = fmaxf(mx, rmx[ww]);
    }
    float norm = (s - mn) / (mx - mn + 1e-8f);
    out[tid] = norm;
    float y = (float)labels[tid];
    float lp = fmaxf(logf(norm), -100.0f);       // log(0) = -inf -> -100, matches ref clamp
    float l1p = fmaxf(log1pf(-norm), -100.0f);
    float term = y * lp + (1.0f - y) * l1p;
    term = wave_reduce_sum(term);
    if (l == 0) rsum[w] = term;
    __syncthreads();
    if (tid == 0) {
        float tot = 0.f;
        for (int ww = 0; ww < 8; ++ww) tot += rsum[ww];
        out[BATCH] = -tot / (float)BATCH;
    }
}

extern "C" void kernel_launch(void* const* d_in, const int* in_sizes, int n_in,
                              void* d_out, int out_size, void* d_ws, size_t ws_size,
                              hipStream_t stream) {
    (void)in_sizes; (void)n_in; (void)out_size; (void)ws_size;
    const float* text = (const float*)d_in[0];
    const float* virt = (const float*)d_in[1];
    const float* gum = (const float*)d_in[2];
    const int* idxb = (const int*)d_in[3];
    const int* esrc = (const int*)d_in[4];
    const int* edst = (const int*)d_in[5];
    const int* label = (const int*)d_in[6];
    float* out = (float*)d_out;

    float* Vn = (float*)d_ws;                    // 3072 f32
    float* Ginv = Vn + K * D;                    // 64 f32
    float* scores = Ginv + K * K;                // 512 f32
    __hip_bfloat16* localb = (__hip_bfloat16*)(scores + BATCH);  // byte off 14592, 16B-aligned

    hipLaunchKernelGGL(prep_kernel, dim3(1), dim3(64), 0, stream, virt, Vn, Ginv);
    hipLaunchKernelGGL(local_kernel, dim3(N_ROWS / 4), dim3(256), 0, stream, text, Vn, Ginv, localb);
    hipLaunchKernelGGL(batch_kernel, dim3(BATCH), dim3(512), 0, stream, localb, gum, idxb, esrc, edst, scores);
    hipLaunchKernelGGL(finalize_kernel, dim3(1), dim3(512), 0, stream, scores, label, out);
}

// Round 2
// 101.900 us; speedup vs baseline: 2.7925x; 2.7925x over previous
//
#include <hip/hip_runtime.h>
#include <hip/hip_bf16.h>
#include <stdint.h>

#define N_ROWS 50000
#define D 384
#define K 8
#define BATCH 512
#define NEGO 128
#define NEDGE 1024

typedef float f32x4 __attribute__((ext_vector_type(4)));
typedef short bf16x8 __attribute__((ext_vector_type(8)));

__device__ __forceinline__ float wave_reduce_sum(float v) {
#pragma unroll
    for (int d = 1; d < 64; d <<= 1) v += __shfl_xor(v, d);
    return v;
}

// ---------------------------------------------------------------------------
// Kernel A: normalize virtual rows, G = Vn Vn^T + eps I, invert 8x8.
// ---------------------------------------------------------------------------
__global__ __launch_bounds__(64) void prep_kernel(const float* __restrict__ virt,
                                                  float* __restrict__ Vn,
                                                  float* __restrict__ Ginv) {
    __shared__ float Vs[K * D];
    __shared__ float Gs[K * K];
    int tid = threadIdx.x;
    for (int t = tid; t < K * D; t += 64) Vs[t] = virt[t];
    __syncthreads();
    for (int k = 0; k < K; ++k) {
        float ss = 0.f;
        for (int t = tid; t < D; t += 64) { float v = Vs[k * D + t]; ss += v * v; }
        ss = wave_reduce_sum(ss);
        float inv = 1.0f / sqrtf(ss + 1e-12f);
        for (int t = tid; t < D; t += 64) {
            float v = Vs[k * D + t] * inv;
            Vs[k * D + t] = v;
            Vn[k * D + t] = v;
        }
        __syncthreads();
    }
    int k = tid >> 3, m = tid & 7;
    float g = 0.f;
    for (int j = 0; j < D; ++j) g += Vs[k * D + j] * Vs[m * D + j];
    if (k == m) g += 1e-4f;
    Gs[tid] = g;
    __syncthreads();
    if (tid == 0) {
        float A[K][K], I8[K][K];
        for (int a = 0; a < K; ++a)
            for (int b2 = 0; b2 < K; ++b2) {
                A[a][b2] = Gs[a * K + b2];
                I8[a][b2] = (a == b2) ? 1.f : 0.f;
            }
        for (int p = 0; p < K; ++p) {
            float piv = 1.0f / A[p][p];
            for (int j = 0; j < K; ++j) { A[p][j] *= piv; I8[p][j] *= piv; }
            for (int r = 0; r < K; ++r)
                if (r != p) {
                    float f = A[r][p];
                    for (int j = 0; j < K; ++j) {
                        A[r][j] -= f * A[p][j];
                        I8[r][j] -= f * I8[p][j];
                    }
                }
        }
        for (int a = 0; a < K; ++a)
            for (int b2 = 0; b2 < K; ++b2) Ginv[a * K + b2] = I8[a][b2];
    }
}

// ---------------------------------------------------------------------------
// Kernel B: per-row projection removal + l2norm, write bf16 local.
// ---------------------------------------------------------------------------
__global__ __launch_bounds__(256) void local_kernel(const float* __restrict__ emb,
                                                    const float* __restrict__ Vn,
                                                    const float* __restrict__ Ginv,
                                                    __hip_bfloat16* __restrict__ outb) {
    __shared__ float Vs[K * D];
    __shared__ float Gs[K * K];
    int tid = threadIdx.x;
    for (int t = tid; t < K * D; t += 256) Vs[t] = Vn[t];
    if (tid < K * K) Gs[tid] = Ginv[tid];
    __syncthreads();
    int w = tid >> 6, l = tid & 63;
    size_t row = (size_t)blockIdx.x * 4 + w;
    const float* x = emb + row * D;
    float xv[6];
#pragma unroll
    for (int t = 0; t < 6; ++t) xv[t] = x[l + 64 * t];
    float ss = 0.f;
#pragma unroll
    for (int t = 0; t < 6; ++t) ss += xv[t] * xv[t];
    float pk[K];
#pragma unroll
    for (int k = 0; k < K; ++k) pk[k] = 0.f;
#pragma unroll
    for (int t = 0; t < 6; ++t) {
        int j = l + 64 * t;
#pragma unroll
        for (int k = 0; k < K; ++k) pk[k] += xv[t] * Vs[k * D + j];
    }
    ss = wave_reduce_sum(ss);
#pragma unroll
    for (int k = 0; k < K; ++k) pk[k] = wave_reduce_sum(pk[k]);
    float invn = 1.0f / sqrtf(ss + 1e-12f);
    float coef[K];
#pragma unroll
    for (int k = 0; k < K; ++k) {
        float c = 0.f;
#pragma unroll
        for (int m = 0; m < K; ++m) c += (pk[m] * invn) * Gs[m * K + k];
        coef[k] = c;
    }
    float rv[6];
    float rss = 0.f;
#pragma unroll
    for (int t = 0; t < 6; ++t) {
        int j = l + 64 * t;
        float r = xv[t] * invn;
#pragma unroll
        for (int k = 0; k < K; ++k) r -= coef[k] * Vs[k * D + j];
        rv[t] = r;
        rss += r * r;
    }
    rss = wave_reduce_sum(rss);
    float invr = 1.0f / sqrtf(rss + 1e-12f);
#pragma unroll
    for (int t = 0; t < 6; ++t)
        outb[row * D + l + 64 * t] = __float2bfloat16(rv[t] * invr);
}

// ---------------------------------------------------------------------------
// Kernel C (MFMA): per ego-graph: gather X (bf16) into swizzled LDS,
// sim = X X^T via mfma_f32_16x16x32_bf16 (wave w owns rows 16w..16w+15),
// fused gumbel softmax + adjacency-bitmask diff + per-batch score.
//
// LDS X: row-major [128][384] bf16, byte addr ^= (row&7)<<4  (bank swizzle;
// row stride 768B is 0 mod 128B, unswizzled would serialize ds_read_b128).
// Gram-matrix note: A and B frags use the SAME slot->element loader, so any
// bijective k-slot mapping gives the correct sum (k-permutation invariant);
// only the C/D layout (col=lane&15, row=(lane>>4)*4+reg, HW-verified) matters.
// ---------------------------------------------------------------------------
__global__ __launch_bounds__(512) void batch_kernel(const __hip_bfloat16* __restrict__ localb,
                                                    const float* __restrict__ gumbel,
                                                    const int* __restrict__ idx_batch,
                                                    const int* __restrict__ edges_src,
                                                    const int* __restrict__ edges_dst,
                                                    float* __restrict__ scores) {
    __shared__ __hip_bfloat16 Xs[NEGO * D];  // 98304 B, swizzled
    __shared__ uint32_t adjmask[NEGO * 4];   // 2048 B
    __shared__ int idxs[NEGO];
    __shared__ float red[8];
    int tid = threadIdx.x;
    int b = blockIdx.x;
    if (tid < NEGO) idxs[tid] = idx_batch[b * NEGO + tid];
    adjmask[tid] = 0u;
    __syncthreads();

    // ---- stage gathered rows into swizzled LDS (4 threads per row) ----
    {
        int row = tid >> 2, seg = tid & 3;
        const uint4* src = (const uint4*)(localb + (size_t)idxs[row] * D);
        char* dstbase = (char*)Xs;
#pragma unroll
        for (int i = 0; i < 12; ++i) {
            int c = seg + 4 * i;  // 16B chunk index within row (48 per row)
            uint4 v = src[c];
            int off = (row * 768 + c * 16) ^ ((row & 7) << 4);
            *(uint4*)(dstbase + off) = v;
        }
    }
    // ---- adjacency bitmask ----
    for (int e = tid; e < NEDGE; e += 512) {
        int s = edges_src[b * NEDGE + e];
        int dd = edges_dst[b * NEDGE + e];
        atomicOr(&adjmask[s * 4 + (dd >> 5)], 1u << (dd & 31));
    }

    int w = tid >> 6, l = tid & 63;
    int c15 = l & 15, g4 = l >> 4;

    // ---- prefetch gumbel into registers (hides under MFMA loop) ----
    float gpre[4][8];
    {
        const float* gb = gumbel + (size_t)b * NEGO * NEGO;
#pragma unroll
        for (int reg = 0; reg < 4; ++reg) {
            int row = w * 16 + g4 * 4 + reg;
#pragma unroll
            for (int t = 0; t < 8; ++t) gpre[reg][t] = gb[row * NEGO + 16 * t + c15];
        }
    }
    __syncthreads();

    // ---- sim strip: rows 16w..16w+15, all 128 cols, via MFMA ----
    f32x4 acc[8];
#pragma unroll
    for (int t = 0; t < 8; ++t) acc[t] = (f32x4){0.f, 0.f, 0.f, 0.f};
    const char* xb = (const char*)Xs;
    int ar = w * 16 + c15;
    int aswz = (ar & 7) << 4;
    for (int ks = 0; ks < 12; ++ks) {
        int kbyte = ks * 64 + g4 * 16;  // (ks*32 + g4*8) bf16 -> bytes
        bf16x8 afrag = *(const bf16x8*)(xb + ((ar * 768 + kbyte) ^ aswz));
#pragma unroll
        for (int t = 0; t < 8; ++t) {
            int br = t * 16 + c15;
            bf16x8 bfrag = *(const bf16x8*)(xb + ((br * 768 + kbyte) ^ ((br & 7) << 4)));
            acc[t] = __builtin_amdgcn_mfma_f32_16x16x32_bf16(afrag, bfrag, acc[t], 0, 0, 0);
        }
    }

    // ---- fused gumbel-softmax + adjacency diff, 4 rows/lane-group ----
    float wave_score = 0.f;
#pragma unroll
    for (int reg = 0; reg < 4; ++reg) {
        int row = w * 16 + g4 * 4 + reg;
        float z[8];
#pragma unroll
        for (int t = 0; t < 8; ++t) {
            float s = acc[t][reg];
            int col = 16 * t + c15;
            if (col == row) s = -1e9f;
            z[t] = s + gpre[reg][t];
        }
        float m = z[0];
#pragma unroll
        for (int t = 1; t < 8; ++t) m = fmaxf(m, z[t]);
#pragma unroll
        for (int d = 1; d < 16; d <<= 1) m = fmaxf(m, __shfl_xor(m, d));
        float e[8], se = 0.f;
#pragma unroll
        for (int t = 0; t < 8; ++t) { e[t] = expf(z[t] - m); se += e[t]; }
#pragma unroll
        for (int d = 1; d < 16; d <<= 1) se += __shfl_xor(se, d);
        float inv = 1.0f / se;
        uint32_t am[4];
#pragma unroll
        for (int q = 0; q < 4; ++q) am[q] = adjmask[row * 4 + q];
        float sq = 0.f;
#pragma unroll
        for (int t = 0; t < 8; ++t) {
            int col = 16 * t + c15;
            float a = (float)((am[col >> 5] >> (col & 31)) & 1u);
            float d0 = a - e[t] * inv;
            sq += d0 * d0;
        }
#pragma unroll
        for (int d = 1; d < 16; d <<= 1) sq += __shfl_xor(sq, d);
        wave_score += sqrtf(sq);
    }
    // sum across the 4 lane-groups (each group's value is group-uniform)
    wave_score += __shfl_xor(wave_score, 16);
    wave_score += __shfl_xor(wave_score, 32);
    if (l == 0) red[w] = wave_score;
    __syncthreads();
    if (tid == 0) {
        float tot = 0.f;
#pragma unroll
        for (int ww = 0; ww < 8; ++ww) tot += red[ww];
        scores[b] = tot * (1.0f / (float)NEGO);
    }
}

// ---------------------------------------------------------------------------
// Kernel D: min-max normalize scores, BCE loss.
// ---------------------------------------------------------------------------
__global__ __launch_bounds__(512) void finalize_kernel(const float* __restrict__ scores,
                                                       const int* __restrict__ labels,
                                                       float* __restrict__ out) {
    __shared__ float rmn[8], rmx[8], rsum[8];
    int tid = threadIdx.x, w = tid >> 6, l = tid & 63;
    float s = scores[tid];
    float mn = s, mx = s;
#pragma unroll
    for (int d = 1; d < 64; d <<= 1) {
        mn = fminf(mn, __shfl_xor(mn, d));
        mx = fmaxf(mx, __shfl_xor(mx, d));
    }
    if (l == 0) { rmn[w] = mn; rmx[w] = mx; }
    __syncthreads();
    mn = rmn[0]; mx = rmx[0];
#pragma unroll
    for (int ww = 1; ww < 8; ++ww) {
        mn = fminf(mn, rmn[ww]);
        mx = fmaxf(mx, rmx[ww]);
    }
    float norm = (s - mn) / (mx - mn + 1e-8f);
    out[tid] = norm;
    float y = (float)labels[tid];
    float lp = fmaxf(logf(norm), -100.0f);
    float l1p = fmaxf(log1pf(-norm), -100.0f);
    float term = y * lp + (1.0f - y) * l1p;
    term = wave_reduce_sum(term);
    if (l == 0) rsum[w] = term;
    __syncthreads();
    if (tid == 0) {
        float tot = 0.f;
        for (int ww = 0; ww < 8; ++ww) tot += rsum[ww];
        out[BATCH] = -tot / (float)BATCH;
    }
}

extern "C" void kernel_launch(void* const* d_in, const int* in_sizes, int n_in,
                              void* d_out, int out_size, void* d_ws, size_t ws_size,
                              hipStream_t stream) {
    (void)in_sizes; (void)n_in; (void)out_size; (void)ws_size;
    const float* text = (const float*)d_in[0];
    const float* virt = (const float*)d_in[1];
    const float* gum = (const float*)d_in[2];
    const int* idxb = (const int*)d_in[3];
    const int* esrc = (const int*)d_in[4];
    const int* edst = (const int*)d_in[5];
    const int* label = (const int*)d_in[6];
    float* out = (float*)d_out;

    float* Vn = (float*)d_ws;
    float* Ginv = Vn + K * D;
    float* scores = Ginv + K * K;
    __hip_bfloat16* localb = (__hip_bfloat16*)(scores + BATCH);

    hipLaunchKernelGGL(prep_kernel, dim3(1), dim3(64), 0, stream, virt, Vn, Ginv);
    hipLaunchKernelGGL(local_kernel, dim3(N_ROWS / 4), dim3(256), 0, stream, text, Vn, Ginv, localb);
    hipLaunchKernelGGL(batch_kernel, dim3(BATCH), dim3(512), 0, stream, localb, gum, idxb, esrc, edst, scores);
    hipLaunchKernelGGL(finalize_kernel, dim3(1), dim3(512), 0, stream, scores, label, out);
}

// Round 3
// 94.633 us; speedup vs baseline: 3.0070x; 1.0768x over previous
//
#include <hip/hip_runtime.h>
#include <hip/hip_bf16.h>
#include <stdint.h>

#define N_ROWS 50000
#define D 384
#define K 8
#define BATCH 512
#define NEGO 128
#define NEDGE 1024

typedef float f32x4 __attribute__((ext_vector_type(4)));
typedef short bf16x8 __attribute__((ext_vector_type(8)));

__device__ __forceinline__ float wave_reduce_sum(float v) {
#pragma unroll
    for (int d = 1; d < 64; d <<= 1) v += __shfl_xor(v, d);
    return v;
}

static __device__ __forceinline__ uint16_t f2bfbits(float f) {
    __hip_bfloat16 h = __float2bfloat16(f);
    union { __hip_bfloat16 h; uint16_t u; } cv;
    cv.h = h;
    return cv.u;
}

// ---------------------------------------------------------------------------
// Kernel A: normalize virtual rows, G = Vn Vn^T + eps I, invert 8x8.
// ---------------------------------------------------------------------------
__global__ __launch_bounds__(64) void prep_kernel(const float* __restrict__ virt,
                                                  float* __restrict__ Vn,
                                                  float* __restrict__ Ginv) {
    __shared__ float Vs[K * D];
    __shared__ float Gs[K * K];
    int tid = threadIdx.x;
    for (int t = tid; t < K * D; t += 64) Vs[t] = virt[t];
    __syncthreads();
    for (int k = 0; k < K; ++k) {
        float ss = 0.f;
        for (int t = tid; t < D; t += 64) { float v = Vs[k * D + t]; ss += v * v; }
        ss = wave_reduce_sum(ss);
        float inv = 1.0f / sqrtf(ss + 1e-12f);
        for (int t = tid; t < D; t += 64) {
            float v = Vs[k * D + t] * inv;
            Vs[k * D + t] = v;
            Vn[k * D + t] = v;
        }
        __syncthreads();
    }
    int k = tid >> 3, m = tid & 7;
    float g = 0.f;
    for (int j = 0; j < D; ++j) g += Vs[k * D + j] * Vs[m * D + j];
    if (k == m) g += 1e-4f;
    Gs[tid] = g;
    __syncthreads();
    if (tid == 0) {
        float A[K][K], I8[K][K];
        for (int a = 0; a < K; ++a)
            for (int b2 = 0; b2 < K; ++b2) {
                A[a][b2] = Gs[a * K + b2];
                I8[a][b2] = (a == b2) ? 1.f : 0.f;
            }
        for (int p = 0; p < K; ++p) {
            float piv = 1.0f / A[p][p];
            for (int j = 0; j < K; ++j) { A[p][j] *= piv; I8[p][j] *= piv; }
            for (int r = 0; r < K; ++r)
                if (r != p) {
                    float f = A[r][p];
                    for (int j = 0; j < K; ++j) {
                        A[r][j] -= f * A[p][j];
                        I8[r][j] -= f * I8[p][j];
                    }
                }
        }
        for (int a = 0; a < K; ++a)
            for (int b2 = 0; b2 < K; ++b2) Ginv[a * K + b2] = I8[a][b2];
    }
}

// ---------------------------------------------------------------------------
// Kernel B: projection removal + l2norm, bf16 out.
// 16-lane group owns 2 rows (float4 per lane: 16 lanes x 4 = 64 floats x 6).
// Block = 128 threads = 8 groups = 16 rows; grid 3125 -> exactly 50000 rows.
// Reductions are 4-step shfl_xor within 16-lane groups; each V ds_read_b128
// feeds FMAs for 2 rows.
// ---------------------------------------------------------------------------
__global__ __launch_bounds__(128) void local_kernel(const float* __restrict__ emb,
                                                    const float* __restrict__ Vn,
                                                    const float* __restrict__ Ginv,
                                                    __hip_bfloat16* __restrict__ outb) {
    __shared__ float Vs[K * D];
    __shared__ float Gs[K * K];
    int tid = threadIdx.x;
    for (int t = tid; t < K * D; t += 128) Vs[t] = Vn[t];
    if (tid < K * K) Gs[tid] = Ginv[tid];
    __syncthreads();
    const float4* Vs4 = (const float4*)Vs;

    int q = tid & 15;
    int grp = tid >> 4;  // 0..7
    size_t rowA = (size_t)blockIdx.x * 16 + grp * 2;
    size_t rowB = rowA + 1;
    const float4* xa = (const float4*)(emb + rowA * D);
    const float4* xb = (const float4*)(emb + rowB * D);

    float4 va[6], vb[6];
#pragma unroll
    for (int t = 0; t < 6; ++t) {
        va[t] = xa[q + 16 * t];
        vb[t] = xb[q + 16 * t];
    }

    float ssa = 0.f, ssb = 0.f;
    float pka[K], pkb[K];
#pragma unroll
    for (int k = 0; k < K; ++k) { pka[k] = 0.f; pkb[k] = 0.f; }
#pragma unroll
    for (int t = 0; t < 6; ++t) {
        float4 a = va[t], b = vb[t];
        ssa += a.x * a.x + a.y * a.y + a.z * a.z + a.w * a.w;
        ssb += b.x * b.x + b.y * b.y + b.z * b.z + b.w * b.w;
        int j = q + 16 * t;
#pragma unroll
        for (int k = 0; k < K; ++k) {
            float4 w = Vs4[k * 96 + j];
            pka[k] += a.x * w.x + a.y * w.y + a.z * w.z + a.w * w.w;
            pkb[k] += b.x * w.x + b.y * w.y + b.z * w.z + b.w * w.w;
        }
    }
#pragma unroll
    for (int d = 1; d < 16; d <<= 1) {
        ssa += __shfl_xor(ssa, d);
        ssb += __shfl_xor(ssb, d);
#pragma unroll
        for (int k = 0; k < K; ++k) {
            pka[k] += __shfl_xor(pka[k], d);
            pkb[k] += __shfl_xor(pkb[k], d);
        }
    }
    float invna = 1.0f / sqrtf(ssa + 1e-12f);
    float invnb = 1.0f / sqrtf(ssb + 1e-12f);
    float ca[K], cb[K];
#pragma unroll
    for (int k = 0; k < K; ++k) {
        float sa = 0.f, sb = 0.f;
#pragma unroll
        for (int m = 0; m < K; ++m) {
            float g = Gs[m * K + k];
            sa += pka[m] * g;
            sb += pkb[m] * g;
        }
        ca[k] = sa * invna;
        cb[k] = sb * invnb;
    }

    float rssa = 0.f, rssb = 0.f;
#pragma unroll
    for (int t = 0; t < 6; ++t) {
        int j = q + 16 * t;
        float4 ra, rb;
        ra.x = va[t].x * invna; ra.y = va[t].y * invna;
        ra.z = va[t].z * invna; ra.w = va[t].w * invna;
        rb.x = vb[t].x * invnb; rb.y = vb[t].y * invnb;
        rb.z = vb[t].z * invnb; rb.w = vb[t].w * invnb;
#pragma unroll
        for (int k = 0; k < K; ++k) {
            float4 w = Vs4[k * 96 + j];
            ra.x -= ca[k] * w.x; ra.y -= ca[k] * w.y;
            ra.z -= ca[k] * w.z; ra.w -= ca[k] * w.w;
            rb.x -= cb[k] * w.x; rb.y -= cb[k] * w.y;
            rb.z -= cb[k] * w.z; rb.w -= cb[k] * w.w;
        }
        va[t] = ra;
        vb[t] = rb;
        rssa += ra.x * ra.x + ra.y * ra.y + ra.z * ra.z + ra.w * ra.w;
        rssb += rb.x * rb.x + rb.y * rb.y + rb.z * rb.z + rb.w * rb.w;
    }
#pragma unroll
    for (int d = 1; d < 16; d <<= 1) {
        rssa += __shfl_xor(rssa, d);
        rssb += __shfl_xor(rssb, d);
    }
    float invra = 1.0f / sqrtf(rssa + 1e-12f);
    float invrb = 1.0f / sqrtf(rssb + 1e-12f);
#pragma unroll
    for (int t = 0; t < 6; ++t) {
        int j = q + 16 * t;
        ushort4 pa, pb;
        pa.x = f2bfbits(va[t].x * invra); pa.y = f2bfbits(va[t].y * invra);
        pa.z = f2bfbits(va[t].z * invra); pa.w = f2bfbits(va[t].w * invra);
        pb.x = f2bfbits(vb[t].x * invrb); pb.y = f2bfbits(vb[t].y * invrb);
        pb.z = f2bfbits(vb[t].z * invrb); pb.w = f2bfbits(vb[t].w * invrb);
        *reinterpret_cast<ushort4*>(outb + rowA * D + (size_t)j * 4) = pa;
        *reinterpret_cast<ushort4*>(outb + rowB * D + (size_t)j * 4) = pb;
    }
}

// ---------------------------------------------------------------------------
// Kernel C (MFMA): per ego-graph: gather X (bf16) into swizzled LDS,
// sim = X X^T via mfma_f32_16x16x32_bf16 (wave w owns rows 16w..16w+15),
// fused gumbel softmax + adjacency-bitmask diff + per-batch score.
// ---------------------------------------------------------------------------
__global__ __launch_bounds__(512) void batch_kernel(const __hip_bfloat16* __restrict__ localb,
                                                    const float* __restrict__ gumbel,
                                                    const int* __restrict__ idx_batch,
                                                    const int* __restrict__ edges_src,
                                                    const int* __restrict__ edges_dst,
                                                    float* __restrict__ scores) {
    __shared__ __hip_bfloat16 Xs[NEGO * D];  // 98304 B, swizzled
    __shared__ uint32_t adjmask[NEGO * 4];   // 2048 B
    __shared__ int idxs[NEGO];
    __shared__ float red[8];
    int tid = threadIdx.x;
    int b = blockIdx.x;
    if (tid < NEGO) idxs[tid] = idx_batch[b * NEGO + tid];
    adjmask[tid] = 0u;
    __syncthreads();

    {
        int row = tid >> 2, seg = tid & 3;
        const uint4* src = (const uint4*)(localb + (size_t)idxs[row] * D);
        char* dstbase = (char*)Xs;
#pragma unroll
        for (int i = 0; i < 12; ++i) {
            int c = seg + 4 * i;
            uint4 v = src[c];
            int off = (row * 768 + c * 16) ^ ((row & 7) << 4);
            *(uint4*)(dstbase + off) = v;
        }
    }
    for (int e = tid; e < NEDGE; e += 512) {
        int s = edges_src[b * NEDGE + e];
        int dd = edges_dst[b * NEDGE + e];
        atomicOr(&adjmask[s * 4 + (dd >> 5)], 1u << (dd & 31));
    }

    int w = tid >> 6, l = tid & 63;
    int c15 = l & 15, g4 = l >> 4;

    float gpre[4][8];
    {
        const float* gb = gumbel + (size_t)b * NEGO * NEGO;
#pragma unroll
        for (int reg = 0; reg < 4; ++reg) {
            int row = w * 16 + g4 * 4 + reg;
#pragma unroll
            for (int t = 0; t < 8; ++t) gpre[reg][t] = gb[row * NEGO + 16 * t + c15];
        }
    }
    __syncthreads();

    f32x4 acc[8];
#pragma unroll
    for (int t = 0; t < 8; ++t) acc[t] = (f32x4){0.f, 0.f, 0.f, 0.f};
    const char* xb = (const char*)Xs;
    int ar = w * 16 + c15;
    int aswz = (ar & 7) << 4;
    for (int ks = 0; ks < 12; ++ks) {
        int kbyte = ks * 64 + g4 * 16;
        bf16x8 afrag = *(const bf16x8*)(xb + ((ar * 768 + kbyte) ^ aswz));
#pragma unroll
        for (int t = 0; t < 8; ++t) {
            int br = t * 16 + c15;
            bf16x8 bfrag = *(const bf16x8*)(xb + ((br * 768 + kbyte) ^ ((br & 7) << 4)));
            acc[t] = __builtin_amdgcn_mfma_f32_16x16x32_bf16(afrag, bfrag, acc[t], 0, 0, 0);
        }
    }

    float wave_score = 0.f;
#pragma unroll
    for (int reg = 0; reg < 4; ++reg) {
        int row = w * 16 + g4 * 4 + reg;
        float z[8];
#pragma unroll
        for (int t = 0; t < 8; ++t) {
            float s = acc[t][reg];
            int col = 16 * t + c15;
            if (col == row) s = -1e9f;
            z[t] = s + gpre[reg][t];
        }
        float m = z[0];
#pragma unroll
        for (int t = 1; t < 8; ++t) m = fmaxf(m, z[t]);
#pragma unroll
        for (int d = 1; d < 16; d <<= 1) m = fmaxf(m, __shfl_xor(m, d));
        float e[8], se = 0.f;
#pragma unroll
        for (int t = 0; t < 8; ++t) { e[t] = expf(z[t] - m); se += e[t]; }
#pragma unroll
        for (int d = 1; d < 16; d <<= 1) se += __shfl_xor(se, d);
        float inv = 1.0f / se;
        uint32_t am[4];
#pragma unroll
        for (int qq = 0; qq < 4; ++qq) am[qq] = adjmask[row * 4 + qq];
        float sq = 0.f;
#pragma unroll
        for (int t = 0; t < 8; ++t) {
            int col = 16 * t + c15;
            float a = (float)((am[col >> 5] >> (col & 31)) & 1u);
            float d0 = a - e[t] * inv;
            sq += d0 * d0;
        }
#pragma unroll
        for (int d = 1; d < 16; d <<= 1) sq += __shfl_xor(sq, d);
        wave_score += sqrtf(sq);
    }
    wave_score += __shfl_xor(wave_score, 16);
    wave_score += __shfl_xor(wave_score, 32);
    if (l == 0) red[w] = wave_score;
    __syncthreads();
    if (tid == 0) {
        float tot = 0.f;
#pragma unroll
        for (int ww = 0; ww < 8; ++ww) tot += red[ww];
        scores[b] = tot * (1.0f / (float)NEGO);
    }
}

// ---------------------------------------------------------------------------
// Kernel D: min-max normalize scores, BCE loss.
// ---------------------------------------------------------------------------
__global__ __launch_bounds__(512) void finalize_kernel(const float* __restrict__ scores,
                                                       const int* __restrict__ labels,
                                                       float* __restrict__ out) {
    __shared__ float rmn[8], rmx[8], rsum[8];
    int tid = threadIdx.x, w = tid >> 6, l = tid & 63;
    float s = scores[tid];
    float mn = s, mx = s;
#pragma unroll
    for (int d = 1; d < 64; d <<= 1) {
        mn = fminf(mn, __shfl_xor(mn, d));
        mx = fmaxf(mx, __shfl_xor(mx, d));
    }
    if (l == 0) { rmn[w] = mn; rmx[w] = mx; }
    __syncthreads();
    mn = rmn[0]; mx = rmx[0];
#pragma unroll
    for (int ww = 1; ww < 8; ++ww) {
        mn = fminf(mn, rmn[ww]);
        mx = fmaxf(mx, rmx[ww]);
    }
    float norm = (s - mn) / (mx - mn + 1e-8f);
    out[tid] = norm;
    float y = (float)labels[tid];
    float lp = fmaxf(logf(norm), -100.0f);
    float l1p = fmaxf(log1pf(-norm), -100.0f);
    float term = y * lp + (1.0f - y) * l1p;
    term = wave_reduce_sum(term);
    if (l == 0) rsum[w] = term;
    __syncthreads();
    if (tid == 0) {
        float tot = 0.f;
        for (int ww = 0; ww < 8; ++ww) tot += rsum[ww];
        out[BATCH] = -tot / (float)BATCH;
    }
}

extern "C" void kernel_launch(void* const* d_in, const int* in_sizes, int n_in,
                              void* d_out, int out_size, void* d_ws, size_t ws_size,
                              hipStream_t stream) {
    (void)in_sizes; (void)n_in; (void)out_size; (void)ws_size;
    const float* text = (const float*)d_in[0];
    const float* virt = (const float*)d_in[1];
    const float* gum = (const float*)d_in[2];
    const int* idxb = (const int*)d_in[3];
    const int* esrc = (const int*)d_in[4];
    const int* edst = (const int*)d_in[5];
    const int* label = (const int*)d_in[6];
    float* out = (float*)d_out;

    float* Vn = (float*)d_ws;
    float* Ginv = Vn + K * D;
    float* scores = Ginv + K * K;
    __hip_bfloat16* localb = (__hip_bfloat16*)(scores + BATCH);

    hipLaunchKernelGGL(prep_kernel, dim3(1), dim3(64), 0, stream, virt, Vn, Ginv);
    hipLaunchKernelGGL(local_kernel, dim3(N_ROWS / 16), dim3(128), 0, stream, text, Vn, Ginv, localb);
    hipLaunchKernelGGL(batch_kernel, dim3(BATCH), dim3(512), 0, stream, localb, gum, idxb, esrc, edst, scores);
    hipLaunchKernelGGL(finalize_kernel, dim3(1), dim3(512), 0, stream, scores, label, out);
}